// Round 1
// baseline (306.832 us; speedup 1.0000x reference)
//
#include <hip/hip_runtime.h>
#include <stdint.h>

// Problem constants (fixed by reference setup_inputs): x (32,384,56,56) fp32,
// weight (384,384) fp32, bias (384,) fp32. K=7 horizontal cyclic shifts.
#define B_   32
#define C_   384
#define H_   56
#define W_   56
#define HW_  (H_*W_)    // 3136
#define NWORD 6         // 384 / 64 bits

// dx per (c % 7): (c + 3) % 7 - 3  ->  {0,1,2,3,-3,-2,-1}
__device__ constexpr int dxtab[7] = {0, 1, 2, 3, -3, -2, -1};

// 7 edge patterns: w = 0,1,2, interior(3..52), 53,54,55.
// invalid-channel bitmasks + valid counts, computed at COMPILE time.
struct Masks {
    unsigned long long inv[7][NWORD];
    int nvalid[7];
};
constexpr Masks make_masks() {
    Masks m{};
    int wv[7] = {0, 1, 2, 3, 53, 54, 55};
    for (int p = 0; p < 7; ++p) {
        int nv = 0;
        for (int c = 0; c < C_; ++c) {
            int dx = (c + 3) % 7 - 3;
            int wp = wv[p] + dx;
            if (wp >= 0 && wp < W_) nv++;
            else m.inv[p][c >> 6] |= 1ull << (c & 63);
        }
        m.nvalid[p] = nv;
    }
    return m;
}
__device__ constexpr Masks MK = make_masks();

// ---------------------------------------------------------------------------
// Prep: pack sign(weight) into 6 uint64 per output channel via __ballot, and
// build C2[pat][o] = Nvalid(pat) + 2*popcount(wbits & invalid(pat)) + bias[o].
// Derivation: out = Nvalid - 2*Mismatch_valid + bias, and with invalid x-bits
// forced to 0: popcount(xm ^ w) = Mismatch_valid + popcount(w & ~mask), so
// out = C2[pat][o] - 2*popcount(xm ^ w).
// ---------------------------------------------------------------------------
__global__ __launch_bounds__(64) void prep_kernel(
        const float* __restrict__ weight, const float* __restrict__ bias,
        unsigned long long* __restrict__ pw, float* __restrict__ C2) {
    int o = blockIdx.x;
    int lane = threadIdx.x;
    unsigned long long words[NWORD];
#pragma unroll
    for (int k = 0; k < NWORD; ++k) {
        float v = weight[o * C_ + k * 64 + lane];
        words[k] = __ballot(v < 0.0f);   // bit c set <=> sign(weight)==-1
    }
    if (lane < NWORD) pw[o * NWORD + lane] = words[lane];
    if (lane < 7) {
        int wb = 0;
#pragma unroll
        for (int k = 0; k < NWORD; ++k)
            wb += __popcll(words[k] & MK.inv[lane][k]);
        C2[lane * C_ + o] = (float)(MK.nvalid[lane] + 2 * wb) + bias[o];
    }
}

// ---------------------------------------------------------------------------
// Main: one thread per pixel (b,h,w). Pack shifted sign(x) bits (invalid -> 0)
// into 6 uint64, then loop 384 output channels: U = sum popcount(xw ^ wbits)
// (wbits are wave-uniform -> scalar loads), out = C2[pat][o] - 2*U.
// ---------------------------------------------------------------------------
__global__ __launch_bounds__(256) void cyclefc_kernel(
        const float* __restrict__ x,
        const unsigned long long* __restrict__ pw,
        const float* __restrict__ C2,
        float* __restrict__ out) {
    unsigned p = blockIdx.x * 256u + threadIdx.x;   // < 100352 exactly
    unsigned w = p % (unsigned)W_;                  // range-known: [0,56)
    unsigned bh = p / (unsigned)W_;
    unsigned h = bh % (unsigned)H_;
    unsigned b = bh / (unsigned)H_;

    const float* xb = x + (size_t)b * C_ * HW_ + h * W_;

    unsigned long long xw[NWORD];
    int cm = 0;  // c % 7, folded at compile time by full unroll
#pragma unroll
    for (int k = 0; k < NWORD; ++k) {
        unsigned long long bits = 0;
#pragma unroll
        for (int j = 0; j < 64; ++j) {
            int c = k * 64 + j;
            int dx = dxtab[cm];
            cm = (cm == 6) ? 0 : cm + 1;
            int wp = (int)w + dx;
            // branchless: clamp address (stays in-row, safe), mask sign bit
            int wpc = wp < 0 ? 0 : (wp > W_ - 1 ? W_ - 1 : wp);
            unsigned u = __float_as_uint(xb[(size_t)c * HW_ + wpc]);
            unsigned sb = (u >> 31) & ((unsigned)wp < (unsigned)W_ ? 1u : 0u);
            bits |= (unsigned long long)sb << j;
        }
        xw[k] = bits;
    }

    int pat = (w < 3u) ? (int)w : ((w >= 53u) ? (int)w - 49 : 3);
    const float* c2p = C2 + pat * C_;
    float* op = out + (size_t)b * C_ * HW_ + h * W_ + w;

#pragma unroll 4
    for (int o = 0; o < C_; ++o) {
        const unsigned long long* wr = pw + o * NWORD;  // uniform -> s_load
        int U = 0;
#pragma unroll
        for (int k = 0; k < NWORD; ++k)
            U += __popcll(xw[k] ^ wr[k]);
        op[(size_t)o * HW_] = c2p[o] - 2.0f * (float)U;
    }
}

extern "C" void kernel_launch(void* const* d_in, const int* in_sizes, int n_in,
                              void* d_out, int out_size, void* d_ws, size_t ws_size,
                              hipStream_t stream) {
    const float* x      = (const float*)d_in[0];
    const float* weight = (const float*)d_in[1];
    const float* bias   = (const float*)d_in[2];
    float* out = (float*)d_out;

    unsigned long long* pw = (unsigned long long*)d_ws;              // 18432 B
    float* C2 = (float*)((char*)d_ws + C_ * NWORD * sizeof(unsigned long long));

    prep_kernel<<<dim3(C_), dim3(64), 0, stream>>>(weight, bias, pw, C2);

    const int npix = B_ * H_ * W_;          // 100352 = 392 * 256
    cyclefc_kernel<<<dim3(npix / 256), dim3(256), 0, stream>>>(x, pw, C2, out);
}